// Round 6
// baseline (419.639 us; speedup 1.0000x reference)
//
#include <hip/hip_runtime.h>
#include <stdint.h>

// MoE: B=4 T=2048 D=512 F=1024 E=8 top_k=2. Inputs/output f32; internals bf16.
#define N_TOK 8192
#define D_DIM 512
#define F_DIM 1024
#define E_NUM 8
#define M_SLOTS (N_TOK * 2)

typedef __bf16 bf16x8 __attribute__((ext_vector_type(8)));
typedef float f32x4 __attribute__((ext_vector_type(4)));

__device__ __forceinline__ ushort f2b(float f) {  // f32 -> bf16 rne
    union { float f; unsigned u; } v; v.f = f;
    unsigned r = v.u + 0x7fffu + ((v.u >> 16) & 1u);
    return (ushort)(r >> 16);
}
__device__ __forceinline__ float b2f(ushort u) {
    union { unsigned i; float f; } v; v.i = ((unsigned)u) << 16; return v.f;
}
__device__ __forceinline__ void gload16(const void* g, void* l) {
    // async global->LDS, 16B/lane; LDS dest is wave-uniform base + lane*16
    __builtin_amdgcn_global_load_lds(
        (const __attribute__((address_space(1))) unsigned int*)g,
        (__attribute__((address_space(3))) unsigned int*)l, 16, 0, 0);
}

// ------ pre: fused {logits + x->bf16 + out zero + cnt zero} and {transposes}
__global__ __launch_bounds__(256) void pre_k(const float* __restrict__ x,
                                             const float* __restrict__ rw,
                                             const float* __restrict__ rb,
                                             ushort* __restrict__ x_bf,
                                             int* __restrict__ tok_e,
                                             float* __restrict__ tok_w,
                                             int* __restrict__ cnt,
                                             const float* __restrict__ wgu,
                                             ushort* __restrict__ wgu_t,
                                             const float* __restrict__ wd,
                                             ushort* __restrict__ wd_t,
                                             float* __restrict__ out) {
    __shared__ ushort tile[64][65];  // used by transpose branch only
    int b = blockIdx.x;
    if (b < N_TOK / 4) {
        // ---------------- logits ----------------
        if (b == 0 && threadIdx.x < 16) cnt[threadIdx.x] = 0;
        int lane = threadIdx.x & 63, wv = threadIdx.x >> 6;
        int t = b * 4 + wv;
        // zero the out row (gemm2 accumulates into out with atomics)
        float4 z4 = (float4){0.f, 0.f, 0.f, 0.f};
        *(float4*)(out + (size_t)t * D_DIM + lane * 8) = z4;
        *(float4*)(out + (size_t)t * D_DIM + lane * 8 + 4) = z4;
        float4 xa = *(const float4*)(x + (size_t)t * D_DIM + lane * 8);
        float4 xb = *(const float4*)(x + (size_t)t * D_DIM + lane * 8 + 4);
        ushort u[8] = {f2b(xa.x), f2b(xa.y), f2b(xa.z), f2b(xa.w),
                       f2b(xb.x), f2b(xb.y), f2b(xb.z), f2b(xb.w)};
        *(uint4*)(x_bf + (size_t)t * D_DIM + lane * 8) = *(const uint4*)u;

        float acc[E_NUM];
#pragma unroll
        for (int e = 0; e < E_NUM; ++e) {
            float4 wa = *(const float4*)(rw + (size_t)e * D_DIM + lane * 8);
            float4 wb = *(const float4*)(rw + (size_t)e * D_DIM + lane * 8 + 4);
            float s = xa.x * wa.x + xa.y * wa.y + xa.z * wa.z + xa.w * wa.w +
                      xb.x * wb.x + xb.y * wb.y + xb.z * wb.z + xb.w * wb.w;
#pragma unroll
            for (int o = 32; o > 0; o >>= 1) s += __shfl_xor(s, o, 64);
            acc[e] = s;
        }
        if (lane == 0) {
            float l[E_NUM];
#pragma unroll
            for (int e = 0; e < E_NUM; ++e) l[e] = acc[e] + rb[e];
            int e0 = 0;
#pragma unroll
            for (int e = 1; e < E_NUM; ++e) if (l[e] > l[e0]) e0 = e;
            int e1 = (e0 == 0) ? 1 : 0;
#pragma unroll
            for (int e = 0; e < E_NUM; ++e) if (e != e0 && l[e] > l[e1]) e1 = e;
            float p1 = __expf(l[e1] - l[e0]);
            float w0 = 1.f / (1.f + p1), w1 = p1 / (1.f + p1);
            tok_e[2 * t] = e0;  tok_e[2 * t + 1] = e1;
            tok_w[2 * t] = w0;  tok_w[2 * t + 1] = w1;
        }
        return;
    }
    // ---------------- transpose ----------------
    int tb = b - N_TOK / 4;
    const float* src; ushort* dst; int R, C, c0, r0;
    if (tb < 2048) {                      // wgu: [e][512][2048], 32x8 tiles
        int e = tb >> 8, rem = tb & 255;
        R = D_DIM; C = 2 * F_DIM;
        src = wgu + (size_t)e * R * C; dst = wgu_t + (size_t)e * R * C;
        c0 = (rem & 31) * 64; r0 = (rem >> 5) * 64;
    } else {                              // wd: [e][1024][512], 8x16 tiles
        int b2 = tb - 2048;
        int e = b2 >> 7, rem = b2 & 127;
        R = F_DIM; C = D_DIM;
        src = wd + (size_t)e * R * C; dst = wd_t + (size_t)e * R * C;
        c0 = (rem & 7) * 64; r0 = (rem >> 3) * 64;
    }
#pragma unroll
    for (int i = 0; i < 4; ++i) {                  // 1024 float4 chunks
        int ch = threadIdx.x + i * 256;
        int row = ch >> 4, pos = ch & 15;
        float4 v = *(const float4*)(src + (size_t)(r0 + row) * C + c0 + pos * 4);
        tile[row][pos * 4 + 0] = f2b(v.x);
        tile[row][pos * 4 + 1] = f2b(v.y);
        tile[row][pos * 4 + 2] = f2b(v.z);
        tile[row][pos * 4 + 3] = f2b(v.w);
    }
    __syncthreads();
#pragma unroll
    for (int i = 0; i < 2; ++i) {                  // 512 uint4 chunks
        int ch = threadIdx.x + i * 256;
        int ocol = ch >> 3, rb_ = ch & 7;
        ushort tmp[8];
#pragma unroll
        for (int j = 0; j < 8; ++j) tmp[j] = tile[rb_ * 8 + j][ocol];
        *(uint4*)(dst + (size_t)(c0 + ocol) * R + r0 + rb_ * 8) = *(const uint4*)tmp;
    }
}

// ------ assign: per-block LDS histogram -> 8 global atomics per block -------
__global__ __launch_bounds__(256) void assign_k(const int* __restrict__ tok_e,
                                                int* __restrict__ cnt,
                                                int* __restrict__ rank) {
    __shared__ int lcnt[E_NUM], lbase[E_NUM];
    int tid = threadIdx.x;
    int i = blockIdx.x * 256 + tid;
    if (tid < E_NUM) lcnt[tid] = 0;
    __syncthreads();
    int e = tok_e[i];
    int intra = atomicAdd(&lcnt[e], 1);
    __syncthreads();
    if (tid < E_NUM) lbase[tid] = atomicAdd(&cnt[tid], lcnt[tid]);
    __syncthreads();
    rank[i] = lbase[e] + intra;
}

// ------ scatter: inline 8-elem prefix of cnt + scatter slot indices --------
__global__ __launch_bounds__(256) void scatter_k(const int* __restrict__ tok_e,
                                                 const int* __restrict__ rank,
                                                 const int* __restrict__ cnt,
                                                 int* __restrict__ ebase,
                                                 int* __restrict__ row_token) {
    __shared__ int eb[E_NUM];
    int tid = threadIdx.x;
    if (tid == 0) {
        int s = 0;
        for (int k = 0; k < E_NUM; ++k) {
            eb[k] = s;
            if (blockIdx.x == 0) ebase[k] = s;
            s += cnt[k];
        }
        if (blockIdx.x == 0) ebase[E_NUM] = s;
    }
    __syncthreads();
    int i = blockIdx.x * 256 + tid;   // slot index
    int pos = eb[tok_e[i]] + rank[i];
    row_token[pos] = i;               // slot idx: token = i>>1, weight = tok_w[i]
}

// ---------------- GEMM1: h = silu(x@Wg) * (x@Wu), grouped by expert ----------
// 128 rows x 64 h-cols (round-2 proven config). BK=32, 3-buffer 2-deep
// pipeline, counted vmcnt(4)+lgkmcnt(0) at barriers.
__global__ __launch_bounds__(256, 3) void gemm1_k(const ushort* __restrict__ x,
                                                  const ushort* __restrict__ wgu_t,
                                                  const int* __restrict__ ebase,
                                                  const int* __restrict__ row_token,
                                                  ushort* __restrict__ h) {
    int e = blockIdx.z;
    int base = ebase[e];
    int cnt = ebase[e + 1] - base;
    int tile0 = blockIdx.y * 128;
    if (tile0 >= cnt) return;
    int c0 = blockIdx.x * 64;            // h-col tile (64 cols)

    __shared__ __align__(16) ushort smem[3 * 8192];  // 48 KB: 3 x (A 8KB | B 8KB)

    int tid = threadIdx.x;
    int lane = tid & 63, wv = tid >> 6;
    int wr = wv >> 1, wc = wv & 1;

    const ushort* asrc[2];
    const ushort* bsrc[2];
#pragma unroll
    for (int i = 0; i < 2; ++i) {
        int c = tid + i * 256;
        int rp = c >> 3, s = c & 7;
        int lp = s ^ (rp & 7);
        int row = 2 * rp + (lp >> 2);            // 0..127
        int q = lp & 3;
        int r = tile0 + row;
        r = (r < cnt) ? r : (cnt - 1);
        int tok = row_token[base + r] >> 1;
        asrc[i] = x + (size_t)tok * D_DIM + q * 8;
        int gc = (row < 64) ? (c0 + row) : (F_DIM + c0 + row - 64);
        bsrc[i] = wgu_t + ((size_t)e * (2 * F_DIM) + gc) * D_DIM + q * 8;
    }

    f32x4 accg[4][2], accu[4][2];
#pragma unroll
    for (int a = 0; a < 4; ++a)
#pragma unroll
        for (int b = 0; b < 2; ++b) {
            accg[a][b] = (f32x4){0.f, 0.f, 0.f, 0.f};
            accu[a][b] = (f32x4){0.f, 0.f, 0.f, 0.f};
        }

    int q = lane >> 4, m = lane & 15;
    int mh = m >> 1;
    int sl = (4 * (m & 1) + q) ^ (mh & 7);       // phys slot, lane-only
    int soff = sl * 8;

    auto stage = [&](ushort* buf, int kk) {
#pragma unroll
        for (int i = 0; i < 2; ++i) {
            int c = tid + i * 256;
            gload16(asrc[i] + kk, buf + (size_t)c * 8);
            gload16(bsrc[i] + kk, buf + 4096 + (size_t)c * 8);
        }
    };
    auto compute = [&](const ushort* la_) {
        const ushort* lb_ = la_ + 4096;
        bf16x8 af[4], bg[2], bu[2];
#pragma unroll
        for (int mt = 0; mt < 4; ++mt)
            af[mt] = *(const bf16x8*)(la_ + (wr * 32 + mt * 8 + mh) * 64 + soff);
#pragma unroll
        for (int nt = 0; nt < 2; ++nt) {
            bg[nt] = *(const bf16x8*)(lb_ + (wc * 16 + nt * 8 + mh) * 64 + soff);
            bu[nt] = *(const bf16x8*)(lb_ + (32 + wc * 16 + nt * 8 + mh) * 64 + soff);
        }
#pragma unroll
        for (int mt = 0; mt < 4; ++mt)
#pragma unroll
            for (int nt = 0; nt < 2; ++nt) {
                accg[mt][nt] = __builtin_amdgcn_mfma_f32_16x16x32_bf16(af[mt], bg[nt], accg[mt][nt], 0, 0, 0);
                accu[mt][nt] = __builtin_amdgcn_mfma_f32_16x16x32_bf16(af[mt], bu[nt], accu[mt][nt], 0, 0, 0);
            }
    };

    ushort* pc = smem;                 // compute buffer (tile t)
    ushort* pn = smem + 8192;          // next resident (tile t+1)
    ushort* pf = smem + 16384;         // being filled (tile t+2)

    stage(pc, 0);
    stage(pn, 32);
    asm volatile("s_waitcnt vmcnt(4) lgkmcnt(0)" ::: "memory");  // tile0 landed
    __builtin_amdgcn_s_barrier();
    __builtin_amdgcn_sched_barrier(0);

    for (int k = 64; k <= D_DIM - 32; k += 32) {      // tiles 2..15
        stage(pf, k);
        compute(pc);
        // drain tile t+1 loads AND own ds_reads of pc; keep t+2 flying
        asm volatile("s_waitcnt vmcnt(4) lgkmcnt(0)" ::: "memory");
        __builtin_amdgcn_s_barrier();
        __builtin_amdgcn_sched_barrier(0);
        ushort* t_ = pc; pc = pn; pn = pf; pf = t_;
    }
    compute(pc);                                      // tile 14
    asm volatile("s_waitcnt vmcnt(0) lgkmcnt(0)" ::: "memory");
    __builtin_amdgcn_s_barrier();
    __builtin_amdgcn_sched_barrier(0);
    compute(pn);                                      // tile 15

    // ---- epilogue: silu*up -> single LDS stage [128][68] -> 16B stores ------
    __syncthreads();                                  // all frag reads done
    ushort* stg = smem;                               // 128*68*2 = 17.4 KB < 48 KB
#pragma unroll
    for (int mt = 0; mt < 4; ++mt)
#pragma unroll
        for (int nt = 0; nt < 2; ++nt) {
            int sc = wc * 32 + nt * 16 + m;
#pragma unroll
            for (int r4 = 0; r4 < 4; ++r4) {
                int rr = wr * 64 + mt * 16 + q * 4 + r4;
                float g = accg[mt][nt][r4];
                float u = accu[mt][nt][r4];
                stg[rr * 68 + sc] = f2b((g / (1.f + __expf(-g))) * u);
            }
        }
    __syncthreads();
#pragma unroll
    for (int p = 0; p < 4; ++p) {
        int c = tid + p * 256;                        // 1024 chunks of 8 ushorts
        int sr = c >> 3, coff = (c & 7) * 8;
        int grow = tile0 + sr;
        if (grow < cnt)
            *(uint4*)(h + (size_t)(base + grow) * F_DIM + c0 + coff) =
                *(const uint4*)(stg + sr * 68 + coff);
    }
}

// -------- GEMM2: out[token] += w_slot * (h @ Wd); 128 rows x 128 cols --------
// Round-4 proven geometry (48 KB, 3 blk/CU, vmcnt(4)); epilogue fuses the
// combine: stage bf16 to LDS, then w*val atomicAdd into out (2 adds/element
// total across grid -> commutative -> deterministic; out zeroed in pre_k).
__global__ __launch_bounds__(256, 3) void gemm2_k(const ushort* __restrict__ h,
                                                  const ushort* __restrict__ wd_t,
                                                  const int* __restrict__ ebase,
                                                  const int* __restrict__ row_token,
                                                  const float* __restrict__ tok_w,
                                                  float* __restrict__ out) {
    int e = blockIdx.z;
    int base = ebase[e];
    int cnt = ebase[e + 1] - base;
    int tile0 = blockIdx.y * 128;
    if (tile0 >= cnt) return;
    int c0 = blockIdx.x * 128;

    __shared__ __align__(16) ushort smem[3 * 8192];  // 48 KB

    int tid = threadIdx.x;
    int lane = tid & 63, wv = tid >> 6;
    int wr = wv >> 1, wc = wv & 1;

    const ushort* asrc[2]; const ushort* bsrc[2];
#pragma unroll
    for (int i = 0; i < 2; ++i) {
        int c = tid + i * 256;
        int rp = c >> 3, s = c & 7;
        int lp = s ^ (rp & 7);
        int row = 2 * rp + (lp >> 2);
        int q = lp & 3;
        int r = tile0 + row;
        r = (r < cnt) ? r : (cnt - 1);
        asrc[i] = h + (size_t)(base + r) * F_DIM + q * 8;
        bsrc[i] = wd_t + ((size_t)e * D_DIM + c0 + row) * F_DIM + q * 8;
    }

    f32x4 acc[4][4];
#pragma unroll
    for (int a = 0; a < 4; ++a)
#pragma unroll
        for (int b = 0; b < 4; ++b) acc[a][b] = (f32x4){0.f, 0.f, 0.f, 0.f};

    int q = lane >> 4, m = lane & 15;
    int mh = m >> 1;
    int sl = (4 * (m & 1) + q) ^ (mh & 7);
    int soff = sl * 8;

    auto stage = [&](ushort* buf, int kk) {
#pragma unroll
        for (int i = 0; i < 2; ++i) {
            int c = tid + i * 256;
            gload16(asrc[i] + kk, buf + (size_t)c * 8);
            gload16(bsrc[i] + kk, buf + 4096 + (size_t)c * 8);
        }
    };
    auto compute = [&](const ushort* la_) {
        const ushort* lb_ = la_ + 4096;
        bf16x8 af[4], bb[4];
#pragma unroll
        for (int mt = 0; mt < 4; ++mt)
            af[mt] = *(const bf16x8*)(la_ + (wr * 32 + mt * 8 + mh) * 64 + soff);
#pragma unroll
        for (int nt = 0; nt < 4; ++nt)
            bb[nt] = *(const bf16x8*)(lb_ + (wc * 32 + nt * 8 + mh) * 64 + soff);
        __builtin_amdgcn_s_setprio(1);
#pragma unroll
        for (int mt = 0; mt < 4; ++mt)
#pragma unroll
            for (int nt = 0; nt < 4; ++nt)
                acc[mt][nt] = __builtin_amdgcn_mfma_f32_16x16x32_bf16(af[mt], bb[nt], acc[mt][nt], 0, 0, 0);
        __builtin_amdgcn_s_setprio(0);
    };

    ushort* pc = smem;
    ushort* pn = smem + 8192;
    ushort* pf = smem + 16384;

    stage(pc, 0);
    stage(pn, 32);
    asm volatile("s_waitcnt vmcnt(4) lgkmcnt(0)" ::: "memory");
    __builtin_amdgcn_s_barrier();
    __builtin_amdgcn_sched_barrier(0);

    for (int k = 64; k <= F_DIM - 32; k += 32) {      // tiles 2..31
        stage(pf, k);
        compute(pc);
        asm volatile("s_waitcnt vmcnt(4) lgkmcnt(0)" ::: "memory");
        __builtin_amdgcn_s_barrier();
        __builtin_amdgcn_sched_barrier(0);
        ushort* t_ = pc; pc = pn; pn = pf; pf = t_;
    }
    compute(pc);
    asm volatile("s_waitcnt vmcnt(0) lgkmcnt(0)" ::: "memory");
    __builtin_amdgcn_s_barrier();
    __builtin_amdgcn_sched_barrier(0);
    compute(pn);

    // epilogue: stage bf16 [128][132] -> weighted f32 atomicAdd into out
    __syncthreads();
    ushort* stg = smem;
#pragma unroll
    for (int mt = 0; mt < 4; ++mt)
#pragma unroll
        for (int nt = 0; nt < 4; ++nt) {
            int scol = wc * 64 + nt * 16 + m;
#pragma unroll
            for (int r4 = 0; r4 < 4; ++r4) {
                int rr = wr * 64 + mt * 16 + q * 4 + r4;
                stg[rr * 132 + scol] = f2b(acc[mt][nt][r4]);
            }
        }
    __syncthreads();
#pragma unroll
    for (int p = 0; p < 8; ++p) {
        int c = tid + p * 256;                        // 2048 chunks of 8 ushorts
        int sr = c >> 4, coff = (c & 15) * 8;
        int grow = tile0 + sr;
        if (grow < cnt) {
            int s_  = row_token[base + grow];         // slot index
            int tok = s_ >> 1;
            float w = tok_w[s_];
            const ushort* sp = stg + sr * 132 + coff;
            float* dst = out + (size_t)tok * D_DIM + c0 + coff;
#pragma unroll
            for (int j = 0; j < 8; ++j)
                atomicAdd(dst + j, w * b2f(sp[j]));
        }
    }
}

extern "C" void kernel_launch(void* const* d_in, const int* in_sizes, int n_in,
                              void* d_out, int out_size, void* d_ws, size_t ws_size,
                              hipStream_t stream) {
    const float* x   = (const float*)d_in[0];
    const float* rw  = (const float*)d_in[1];
    const float* rb  = (const float*)d_in[2];
    const float* wgu = (const float*)d_in[3];
    const float* wd  = (const float*)d_in[4];
    float* out = (float*)d_out;

    char* ws = (char*)d_ws;
    size_t off = 0;
    auto alloc = [&](size_t bytes) -> void* {
        void* p = ws + off;
        off += (bytes + 255) & ~(size_t)255;
        return p;
    };
    ushort* wgu_t     = (ushort*)alloc((size_t)E_NUM * 2 * F_DIM * D_DIM * 2);  // 16.8 MB
    ushort* wd_t      = (ushort*)alloc((size_t)E_NUM * D_DIM * F_DIM * 2);      //  8.4 MB
    ushort* x_bf      = (ushort*)alloc((size_t)N_TOK * D_DIM * 2);              //  8.4 MB
    ushort* hbuf      = (ushort*)alloc((size_t)M_SLOTS * F_DIM * 2);            // 33.6 MB
    int*    row_token = (int*)alloc(M_SLOTS * 4);
    int*    tok_e     = (int*)alloc(M_SLOTS * 4);
    int*    rankbuf   = (int*)alloc(M_SLOTS * 4);
    float*  tok_w     = (float*)alloc(M_SLOTS * 4);
    int*    cnt       = (int*)alloc(64);
    int*    ebase     = (int*)alloc(64);

    pre_k<<<N_TOK / 4 + 3072, 256, 0, stream>>>(x, rw, rb, x_bf, tok_e, tok_w, cnt,
                                                wgu, wgu_t, wd, wd_t, out);
    assign_k<<<M_SLOTS / 256, 256, 0, stream>>>(tok_e, cnt, rankbuf);
    scatter_k<<<M_SLOTS / 256, 256, 0, stream>>>(tok_e, rankbuf, cnt, ebase, row_token);
    gemm1_k<<<dim3(16, 32, E_NUM), 256, 0, stream>>>(x_bf, wgu_t, ebase, row_token, hbuf);
    gemm2_k<<<dim3(4, 32, E_NUM), 256, 0, stream>>>(hbuf, wd_t, ebase, row_token, tok_w, out);
}

// Round 7
// 204.617 us; speedup vs baseline: 2.0509x; 2.0509x over previous
//
#include <hip/hip_runtime.h>
#include <stdint.h>

// MoE: B=4 T=2048 D=512 F=1024 E=8 top_k=2. Inputs/output f32; internals bf16.
#define N_TOK 8192
#define D_DIM 512
#define F_DIM 1024
#define E_NUM 8
#define M_SLOTS (N_TOK * 2)

typedef __bf16 bf16x8 __attribute__((ext_vector_type(8)));
typedef float f32x4 __attribute__((ext_vector_type(4)));

__device__ __forceinline__ ushort f2b(float f) {  // f32 -> bf16 rne
    union { float f; unsigned u; } v; v.f = f;
    unsigned r = v.u + 0x7fffu + ((v.u >> 16) & 1u);
    return (ushort)(r >> 16);
}
__device__ __forceinline__ float b2f(ushort u) {
    union { unsigned i; float f; } v; v.i = ((unsigned)u) << 16; return v.f;
}
__device__ __forceinline__ void gload16(const void* g, void* l) {
    // async global->LDS, 16B/lane; LDS dest is wave-uniform base + lane*16
    __builtin_amdgcn_global_load_lds(
        (const __attribute__((address_space(1))) unsigned int*)g,
        (__attribute__((address_space(3))) unsigned int*)l, 16, 0, 0);
}

// ------ pre: fused {logits + x->bf16 + cnt zero} and {weight transposes} ----
__global__ __launch_bounds__(256) void pre_k(const float* __restrict__ x,
                                             const float* __restrict__ rw,
                                             const float* __restrict__ rb,
                                             ushort* __restrict__ x_bf,
                                             int* __restrict__ tok_e,
                                             float* __restrict__ tok_w,
                                             int* __restrict__ cnt,
                                             const float* __restrict__ wgu,
                                             ushort* __restrict__ wgu_t,
                                             const float* __restrict__ wd,
                                             ushort* __restrict__ wd_t) {
    __shared__ ushort tile[64][65];  // used by transpose branch only
    int b = blockIdx.x;
    if (b < N_TOK / 4) {
        // ---------------- logits ----------------
        if (b == 0 && threadIdx.x < 16) cnt[threadIdx.x] = 0;
        int lane = threadIdx.x & 63, wv = threadIdx.x >> 6;
        int t = b * 4 + wv;
        float4 xa = *(const float4*)(x + (size_t)t * D_DIM + lane * 8);
        float4 xb = *(const float4*)(x + (size_t)t * D_DIM + lane * 8 + 4);
        ushort u[8] = {f2b(xa.x), f2b(xa.y), f2b(xa.z), f2b(xa.w),
                       f2b(xb.x), f2b(xb.y), f2b(xb.z), f2b(xb.w)};
        *(uint4*)(x_bf + (size_t)t * D_DIM + lane * 8) = *(const uint4*)u;

        float acc[E_NUM];
#pragma unroll
        for (int e = 0; e < E_NUM; ++e) {
            float4 wa = *(const float4*)(rw + (size_t)e * D_DIM + lane * 8);
            float4 wb = *(const float4*)(rw + (size_t)e * D_DIM + lane * 8 + 4);
            float s = xa.x * wa.x + xa.y * wa.y + xa.z * wa.z + xa.w * wa.w +
                      xb.x * wb.x + xb.y * wb.y + xb.z * wb.z + xb.w * wb.w;
#pragma unroll
            for (int o = 32; o > 0; o >>= 1) s += __shfl_xor(s, o, 64);
            acc[e] = s;
        }
        if (lane == 0) {
            float l[E_NUM];
#pragma unroll
            for (int e = 0; e < E_NUM; ++e) l[e] = acc[e] + rb[e];
            int e0 = 0;
#pragma unroll
            for (int e = 1; e < E_NUM; ++e) if (l[e] > l[e0]) e0 = e;
            int e1 = (e0 == 0) ? 1 : 0;
#pragma unroll
            for (int e = 0; e < E_NUM; ++e) if (e != e0 && l[e] > l[e1]) e1 = e;
            float p1 = __expf(l[e1] - l[e0]);
            float w0 = 1.f / (1.f + p1), w1 = p1 / (1.f + p1);
            tok_e[2 * t] = e0;  tok_e[2 * t + 1] = e1;
            tok_w[2 * t] = w0;  tok_w[2 * t + 1] = w1;
        }
        return;
    }
    // ---------------- transpose ----------------
    int tb = b - N_TOK / 4;
    const float* src; ushort* dst; int R, C, c0, r0;
    if (tb < 2048) {                      // wgu: [e][512][2048], 32x8 tiles
        int e = tb >> 8, rem = tb & 255;
        R = D_DIM; C = 2 * F_DIM;
        src = wgu + (size_t)e * R * C; dst = wgu_t + (size_t)e * R * C;
        c0 = (rem & 31) * 64; r0 = (rem >> 5) * 64;
    } else {                              // wd: [e][1024][512], 8x16 tiles
        int b2 = tb - 2048;
        int e = b2 >> 7, rem = b2 & 127;
        R = F_DIM; C = D_DIM;
        src = wd + (size_t)e * R * C; dst = wd_t + (size_t)e * R * C;
        c0 = (rem & 7) * 64; r0 = (rem >> 3) * 64;
    }
#pragma unroll
    for (int i = 0; i < 4; ++i) {                  // 1024 float4 chunks
        int ch = threadIdx.x + i * 256;
        int row = ch >> 4, pos = ch & 15;
        float4 v = *(const float4*)(src + (size_t)(r0 + row) * C + c0 + pos * 4);
        tile[row][pos * 4 + 0] = f2b(v.x);
        tile[row][pos * 4 + 1] = f2b(v.y);
        tile[row][pos * 4 + 2] = f2b(v.z);
        tile[row][pos * 4 + 3] = f2b(v.w);
    }
    __syncthreads();
#pragma unroll
    for (int i = 0; i < 2; ++i) {                  // 512 uint4 chunks
        int ch = threadIdx.x + i * 256;
        int ocol = ch >> 3, rb_ = ch & 7;
        ushort tmp[8];
#pragma unroll
        for (int j = 0; j < 8; ++j) tmp[j] = tile[rb_ * 8 + j][ocol];
        *(uint4*)(dst + (size_t)(c0 + ocol) * R + r0 + rb_ * 8) = *(const uint4*)tmp;
    }
}

// ------ assign: per-block LDS histogram -> 8 global atomics per block -------
__global__ __launch_bounds__(256) void assign_k(const int* __restrict__ tok_e,
                                                int* __restrict__ cnt,
                                                int* __restrict__ rank) {
    __shared__ int lcnt[E_NUM], lbase[E_NUM];
    int tid = threadIdx.x;
    int i = blockIdx.x * 256 + tid;
    if (tid < E_NUM) lcnt[tid] = 0;
    __syncthreads();
    int e = tok_e[i];
    int intra = atomicAdd(&lcnt[e], 1);
    __syncthreads();
    if (tid < E_NUM) lbase[tid] = atomicAdd(&cnt[tid], lcnt[tid]);
    __syncthreads();
    rank[i] = lbase[e] + intra;
}

// ------ scatter: inline 8-elem prefix of cnt + scatter rows -----------------
__global__ __launch_bounds__(256) void scatter_k(const int* __restrict__ tok_e,
                                                 const int* __restrict__ rank,
                                                 const int* __restrict__ cnt,
                                                 int* __restrict__ ebase,
                                                 int* __restrict__ row_token,
                                                 int* __restrict__ tok_pos) {
    __shared__ int eb[E_NUM];
    int tid = threadIdx.x;
    if (tid == 0) {
        int s = 0;
        for (int k = 0; k < E_NUM; ++k) {
            eb[k] = s;
            if (blockIdx.x == 0) ebase[k] = s;
            s += cnt[k];
        }
        if (blockIdx.x == 0) ebase[E_NUM] = s;
    }
    __syncthreads();
    int i = blockIdx.x * 256 + tid;   // slot index
    int pos = eb[tok_e[i]] + rank[i];
    row_token[pos] = i >> 1;
    tok_pos[i] = pos;
}

// ---------------- GEMM1: h = silu(x@Wg) * (x@Wu), grouped by expert ----------
// 128 rows x 64 h-cols (measured 54-55 us). BK=32, 3-buffer 2-deep pipeline,
// counted vmcnt(4)+lgkmcnt(0) at barriers.
__global__ __launch_bounds__(256, 3) void gemm1_k(const ushort* __restrict__ x,
                                                  const ushort* __restrict__ wgu_t,
                                                  const int* __restrict__ ebase,
                                                  const int* __restrict__ row_token,
                                                  ushort* __restrict__ h) {
    int e = blockIdx.z;
    int base = ebase[e];
    int cnt = ebase[e + 1] - base;
    int tile0 = blockIdx.y * 128;
    if (tile0 >= cnt) return;
    int c0 = blockIdx.x * 64;            // h-col tile (64 cols)

    __shared__ __align__(16) ushort smem[3 * 8192];  // 48 KB: 3 x (A 8KB | B 8KB)

    int tid = threadIdx.x;
    int lane = tid & 63, wv = tid >> 6;
    int wr = wv >> 1, wc = wv & 1;

    const ushort* asrc[2];
    const ushort* bsrc[2];
#pragma unroll
    for (int i = 0; i < 2; ++i) {
        int c = tid + i * 256;
        int rp = c >> 3, s = c & 7;
        int lp = s ^ (rp & 7);
        int row = 2 * rp + (lp >> 2);            // 0..127
        int q = lp & 3;
        int r = tile0 + row;
        r = (r < cnt) ? r : (cnt - 1);
        int tok = row_token[base + r];
        asrc[i] = x + (size_t)tok * D_DIM + q * 8;
        int gc = (row < 64) ? (c0 + row) : (F_DIM + c0 + row - 64);
        bsrc[i] = wgu_t + ((size_t)e * (2 * F_DIM) + gc) * D_DIM + q * 8;
    }

    f32x4 accg[4][2], accu[4][2];
#pragma unroll
    for (int a = 0; a < 4; ++a)
#pragma unroll
        for (int b = 0; b < 2; ++b) {
            accg[a][b] = (f32x4){0.f, 0.f, 0.f, 0.f};
            accu[a][b] = (f32x4){0.f, 0.f, 0.f, 0.f};
        }

    int q = lane >> 4, m = lane & 15;
    int mh = m >> 1;
    int sl = (4 * (m & 1) + q) ^ (mh & 7);       // phys slot, lane-only
    int soff = sl * 8;

    auto stage = [&](ushort* buf, int kk) {
#pragma unroll
        for (int i = 0; i < 2; ++i) {
            int c = tid + i * 256;
            gload16(asrc[i] + kk, buf + (size_t)c * 8);
            gload16(bsrc[i] + kk, buf + 4096 + (size_t)c * 8);
        }
    };
    auto compute = [&](const ushort* la_) {
        const ushort* lb_ = la_ + 4096;
        bf16x8 af[4], bg[2], bu[2];
#pragma unroll
        for (int mt = 0; mt < 4; ++mt)
            af[mt] = *(const bf16x8*)(la_ + (wr * 32 + mt * 8 + mh) * 64 + soff);
#pragma unroll
        for (int nt = 0; nt < 2; ++nt) {
            bg[nt] = *(const bf16x8*)(lb_ + (wc * 16 + nt * 8 + mh) * 64 + soff);
            bu[nt] = *(const bf16x8*)(lb_ + (32 + wc * 16 + nt * 8 + mh) * 64 + soff);
        }
#pragma unroll
        for (int mt = 0; mt < 4; ++mt)
#pragma unroll
            for (int nt = 0; nt < 2; ++nt) {
                accg[mt][nt] = __builtin_amdgcn_mfma_f32_16x16x32_bf16(af[mt], bg[nt], accg[mt][nt], 0, 0, 0);
                accu[mt][nt] = __builtin_amdgcn_mfma_f32_16x16x32_bf16(af[mt], bu[nt], accu[mt][nt], 0, 0, 0);
            }
    };

    ushort* pc = smem;                 // compute buffer (tile t)
    ushort* pn = smem + 8192;          // next resident (tile t+1)
    ushort* pf = smem + 16384;         // being filled (tile t+2)

    stage(pc, 0);
    stage(pn, 32);
    asm volatile("s_waitcnt vmcnt(4) lgkmcnt(0)" ::: "memory");  // tile0 landed
    __builtin_amdgcn_s_barrier();
    __builtin_amdgcn_sched_barrier(0);

    for (int k = 64; k <= D_DIM - 32; k += 32) {      // tiles 2..15
        stage(pf, k);
        compute(pc);
        // drain tile t+1 loads AND own ds_reads of pc; keep t+2 flying
        asm volatile("s_waitcnt vmcnt(4) lgkmcnt(0)" ::: "memory");
        __builtin_amdgcn_s_barrier();
        __builtin_amdgcn_sched_barrier(0);
        ushort* t_ = pc; pc = pn; pn = pf; pf = t_;
    }
    compute(pc);                                      // tile 14
    asm volatile("s_waitcnt vmcnt(0) lgkmcnt(0)" ::: "memory");
    __builtin_amdgcn_s_barrier();
    __builtin_amdgcn_sched_barrier(0);
    compute(pn);                                      // tile 15

    // ---- epilogue: silu*up -> single LDS stage [128][68] -> 16B stores ------
    __syncthreads();                                  // all frag reads done
    ushort* stg = smem;                               // 128*68*2 = 17.4 KB < 48 KB
#pragma unroll
    for (int mt = 0; mt < 4; ++mt)
#pragma unroll
        for (int nt = 0; nt < 2; ++nt) {
            int sc = wc * 32 + nt * 16 + m;
#pragma unroll
            for (int r4 = 0; r4 < 4; ++r4) {
                int rr = wr * 64 + mt * 16 + q * 4 + r4;
                float g = accg[mt][nt][r4];
                float u = accu[mt][nt][r4];
                stg[rr * 68 + sc] = f2b((g / (1.f + __expf(-g))) * u);
            }
        }
    __syncthreads();
#pragma unroll
    for (int p = 0; p < 4; ++p) {
        int c = tid + p * 256;                        // 1024 chunks of 8 ushorts
        int sr = c >> 3, coff = (c & 7) * 8;
        int grow = tile0 + sr;
        if (grow < cnt)
            *(uint4*)(h + (size_t)(base + grow) * F_DIM + c0 + coff) =
                *(const uint4*)(stg + sr * 68 + coff);
    }
}

// -------- GEMM2: slot = h @ Wd (bf16); 128 rows x 128 cols (round-4 cfg) -----
__global__ __launch_bounds__(256, 3) void gemm2_k(const ushort* __restrict__ h,
                                                  const ushort* __restrict__ wd_t,
                                                  const int* __restrict__ ebase,
                                                  ushort* __restrict__ slot) {
    int e = blockIdx.z;
    int base = ebase[e];
    int cnt = ebase[e + 1] - base;
    int tile0 = blockIdx.y * 128;
    if (tile0 >= cnt) return;
    int c0 = blockIdx.x * 128;

    __shared__ __align__(16) ushort smem[3 * 8192];  // 48 KB

    int tid = threadIdx.x;
    int lane = tid & 63, wv = tid >> 6;
    int wr = wv >> 1, wc = wv & 1;

    const ushort* asrc[2]; const ushort* bsrc[2];
#pragma unroll
    for (int i = 0; i < 2; ++i) {
        int c = tid + i * 256;
        int rp = c >> 3, s = c & 7;
        int lp = s ^ (rp & 7);
        int row = 2 * rp + (lp >> 2);
        int q = lp & 3;
        int r = tile0 + row;
        r = (r < cnt) ? r : (cnt - 1);
        asrc[i] = h + (size_t)(base + r) * F_DIM + q * 8;
        bsrc[i] = wd_t + ((size_t)e * D_DIM + c0 + row) * F_DIM + q * 8;
    }

    f32x4 acc[4][4];
#pragma unroll
    for (int a = 0; a < 4; ++a)
#pragma unroll
        for (int b = 0; b < 4; ++b) acc[a][b] = (f32x4){0.f, 0.f, 0.f, 0.f};

    int q = lane >> 4, m = lane & 15;
    int mh = m >> 1;
    int sl = (4 * (m & 1) + q) ^ (mh & 7);
    int soff = sl * 8;

    auto stage = [&](ushort* buf, int kk) {
#pragma unroll
        for (int i = 0; i < 2; ++i) {
            int c = tid + i * 256;
            gload16(asrc[i] + kk, buf + (size_t)c * 8);
            gload16(bsrc[i] + kk, buf + 4096 + (size_t)c * 8);
        }
    };
    auto compute = [&](const ushort* la_) {
        const ushort* lb_ = la_ + 4096;
        bf16x8 af[4], bb[4];
#pragma unroll
        for (int mt = 0; mt < 4; ++mt)
            af[mt] = *(const bf16x8*)(la_ + (wr * 32 + mt * 8 + mh) * 64 + soff);
#pragma unroll
        for (int nt = 0; nt < 4; ++nt)
            bb[nt] = *(const bf16x8*)(lb_ + (wc * 32 + nt * 8 + mh) * 64 + soff);
        __builtin_amdgcn_s_setprio(1);
#pragma unroll
        for (int mt = 0; mt < 4; ++mt)
#pragma unroll
            for (int nt = 0; nt < 4; ++nt)
                acc[mt][nt] = __builtin_amdgcn_mfma_f32_16x16x32_bf16(af[mt], bb[nt], acc[mt][nt], 0, 0, 0);
        __builtin_amdgcn_s_setprio(0);
    };

    ushort* pc = smem;
    ushort* pn = smem + 8192;
    ushort* pf = smem + 16384;

    stage(pc, 0);
    stage(pn, 32);
    asm volatile("s_waitcnt vmcnt(4) lgkmcnt(0)" ::: "memory");
    __builtin_amdgcn_s_barrier();
    __builtin_amdgcn_sched_barrier(0);

    for (int k = 64; k <= F_DIM - 32; k += 32) {      // tiles 2..31
        stage(pf, k);
        compute(pc);
        asm volatile("s_waitcnt vmcnt(4) lgkmcnt(0)" ::: "memory");
        __builtin_amdgcn_s_barrier();
        __builtin_amdgcn_sched_barrier(0);
        ushort* t_ = pc; pc = pn; pn = pf; pf = t_;
    }
    compute(pc);
    asm volatile("s_waitcnt vmcnt(0) lgkmcnt(0)" ::: "memory");
    __builtin_amdgcn_s_barrier();
    __builtin_amdgcn_sched_barrier(0);
    compute(pn);

    // epilogue: single stage [128][132] (33.8 KB) -> coalesced bf16 slot rows
    __syncthreads();
    ushort* stg = smem;
#pragma unroll
    for (int mt = 0; mt < 4; ++mt)
#pragma unroll
        for (int nt = 0; nt < 4; ++nt) {
            int scol = wc * 64 + nt * 16 + m;
#pragma unroll
            for (int r4 = 0; r4 < 4; ++r4) {
                int rr = wr * 64 + mt * 16 + q * 4 + r4;
                stg[rr * 132 + scol] = f2b(acc[mt][nt][r4]);
            }
        }
    __syncthreads();
#pragma unroll
    for (int p = 0; p < 8; ++p) {
        int c = tid + p * 256;                        // 2048 chunks of 8 ushorts
        int sr = c >> 4, coff = (c & 15) * 8;
        int grow = tile0 + sr;
        if (grow < cnt)
            *(uint4*)(slot + (size_t)(base + grow) * D_DIM + c0 + coff) =
                *(const uint4*)(stg + sr * 132 + coff);
    }
}

// ------ combine: out[t] = w0*slot[p0] + w1*slot[p1]  (wave per token) -------
__global__ __launch_bounds__(256) void combine_k(const ushort* __restrict__ slot,
                                                 const int* __restrict__ tok_pos,
                                                 const float* __restrict__ tok_w,
                                                 float* __restrict__ out) {
    int lane = threadIdx.x & 63, wv = threadIdx.x >> 6;
    int t = blockIdx.x * 4 + wv;
    int p0 = tok_pos[2 * t], p1 = tok_pos[2 * t + 1];
    float w0 = tok_w[2 * t], w1 = tok_w[2 * t + 1];
    uint4 s0 = *(const uint4*)(slot + (size_t)p0 * D_DIM + lane * 8);
    uint4 s1 = *(const uint4*)(slot + (size_t)p1 * D_DIM + lane * 8);
    const ushort* a = (const ushort*)&s0;
    const ushort* b = (const ushort*)&s1;
    float o[8];
#pragma unroll
    for (int j = 0; j < 8; ++j) o[j] = w0 * b2f(a[j]) + w1 * b2f(b[j]);
    float* dst = out + (size_t)t * D_DIM + lane * 8;
    *(float4*)dst = (float4){o[0], o[1], o[2], o[3]};
    *(float4*)(dst + 4) = (float4){o[4], o[5], o[6], o[7]};
}

extern "C" void kernel_launch(void* const* d_in, const int* in_sizes, int n_in,
                              void* d_out, int out_size, void* d_ws, size_t ws_size,
                              hipStream_t stream) {
    const float* x   = (const float*)d_in[0];
    const float* rw  = (const float*)d_in[1];
    const float* rb  = (const float*)d_in[2];
    const float* wgu = (const float*)d_in[3];
    const float* wd  = (const float*)d_in[4];
    float* out = (float*)d_out;

    char* ws = (char*)d_ws;
    size_t off = 0;
    auto alloc = [&](size_t bytes) -> void* {
        void* p = ws + off;
        off += (bytes + 255) & ~(size_t)255;
        return p;
    };
    ushort* wgu_t     = (ushort*)alloc((size_t)E_NUM * 2 * F_DIM * D_DIM * 2);  // 16.8 MB
    ushort* wd_t      = (ushort*)alloc((size_t)E_NUM * D_DIM * F_DIM * 2);      //  8.4 MB
    ushort* x_bf      = (ushort*)alloc((size_t)N_TOK * D_DIM * 2);              //  8.4 MB
    ushort* hbuf      = (ushort*)alloc((size_t)M_SLOTS * F_DIM * 2);            // 33.6 MB
    ushort* slot      = (ushort*)alloc((size_t)M_SLOTS * D_DIM * 2);            // 16.8 MB
    int*    row_token = (int*)alloc(M_SLOTS * 4);
    int*    tok_e     = (int*)alloc(M_SLOTS * 4);
    int*    rankbuf   = (int*)alloc(M_SLOTS * 4);
    float*  tok_w     = (float*)alloc(M_SLOTS * 4);
    int*    tok_pos   = (int*)alloc(M_SLOTS * 4);
    int*    cnt       = (int*)alloc(64);
    int*    ebase     = (int*)alloc(64);

    pre_k<<<N_TOK / 4 + 3072, 256, 0, stream>>>(x, rw, rb, x_bf, tok_e, tok_w, cnt,
                                                wgu, wgu_t, wd, wd_t);
    assign_k<<<M_SLOTS / 256, 256, 0, stream>>>(tok_e, cnt, rankbuf);
    scatter_k<<<M_SLOTS / 256, 256, 0, stream>>>(tok_e, rankbuf, cnt, ebase, row_token, tok_pos);
    gemm1_k<<<dim3(16, 32, E_NUM), 256, 0, stream>>>(x_bf, wgu_t, ebase, row_token, hbuf);
    gemm2_k<<<dim3(4, 32, E_NUM), 256, 0, stream>>>(hbuf, wd_t, ebase, slot);
    combine_k<<<N_TOK / 4, 256, 0, stream>>>(slot, tok_pos, tok_w, out);
}